// Round 8
// baseline (1268.642 us; speedup 1.0000x reference)
//
#include <hip/hip_runtime.h>
#include <math.h>

#define DEVINL __device__ __forceinline__

constexpr int S_   = 1024;
constexpr int H_   = 512;
constexpr int NH_  = 8;
constexpr int L_   = 4;
constexpr int HD_  = 64;
constexpr int MLP_ = 2048;
constexpr int OUT_ = 128;
constexpr int B_   = 2;
constexpr int BS_  = 2048;   // B*S
constexpr int KTOP_ = 204;

typedef __bf16 bf16x8 __attribute__((ext_vector_type(8)));
typedef float f32x4 __attribute__((ext_vector_type(4)));

DEVINL unsigned short f2b(float f) {
  unsigned int u = __float_as_uint(f);
  unsigned int r = (u + 0x7fffu + ((u >> 16) & 1u)) >> 16;  // RNE
  return (unsigned short)r;
}

// async global -> LDS, 16 B per lane; lds dst must be wave-uniform base,
// HW writes base + lane*16. Global src is per-lane.
DEVINL void gload16(const unsigned short* g, unsigned short* l) {
  __builtin_amdgcn_global_load_lds(
      (const __attribute__((address_space(1))) unsigned int*)g,
      (__attribute__((address_space(3))) unsigned int*)l,
      16, 0, 0);
}

// ---------------------------------------------------------------------------
// Unified prep kernel: all weight transposes (f32 [z][R][C] -> bf16 [z][C][R])
// + input projection + positional encoding. Flat grid of 13376 blocks.
// ---------------------------------------------------------------------------
__global__ __launch_bounds__(256) void prep_kernel(
    const float* __restrict__ qw, const float* __restrict__ kw,
    const float* __restrict__ vw, const float* __restrict__ ow,
    const float* __restrict__ w1, const float* __restrict__ w2,
    const float* __restrict__ outw,
    const float* __restrict__ x, const float* __restrict__ in_w,
    const float* __restrict__ in_b,
    unsigned short* __restrict__ Wqkvt, unsigned short* __restrict__ Wot,
    unsigned short* __restrict__ W1t, unsigned short* __restrict__ W2t,
    unsigned short* __restrict__ OWt, float* __restrict__ h)
{
  const int bid = blockIdx.x;
  if (bid >= 12352) {
    // ---- input_pe ----
    const int idx = bid - 12352;
    const int row = idx * 2 + (threadIdx.x >> 7);
    const int s = row & (S_ - 1);
    const int c = (threadIdx.x & 127) * 4;
    const float xv = x[row];
    const float4 wv = *(const float4*)(in_w + c);
    const float4 bv = *(const float4*)(in_b + c);
    const float* wp = (const float*)&wv;
    const float* bp = (const float*)&bv;
    float o[4];
#pragma unroll
    for (int j = 0; j < 4; j++) {
      const int cc = c + j;
      const float di = expf(-(float)(cc & ~1) * (9.210340371976184f / 512.0f));
      const float ang = (float)s * di;
      const float pe = (cc & 1) ? cosf(ang) : sinf(ang);
      o[j] = xv * wp[j] + bp[j] + pe;
    }
    *(float4*)(h + (size_t)row * H_ + c) = make_float4(o[0], o[1], o[2], o[3]);
    return;
  }
  // ---- transposes ----
  const float* src; unsigned short* dst; int R, C, cx, ry;
  if (bid < 4096) {
    const int z = bid >> 8, rem = bid & 255;
    const int which = z >> 2, l = z & 3;
    src = (which == 0 ? qw : which == 1 ? kw : which == 2 ? vw : ow)
          + (size_t)l * 512 * 512;
    dst = (which < 3)
        ? (Wqkvt + (size_t)l * 1536 * 512 + (size_t)which * 512 * 512)
        : (Wot + (size_t)l * 512 * 512);
    R = 512; C = 512; cx = rem & 15; ry = rem >> 4;
  } else if (bid < 8192) {
    const int idx = bid - 4096, z = idx >> 10, rem = idx & 1023;
    src = w1 + (size_t)z * 512 * 2048;
    dst = W1t + (size_t)z * 2048 * 512;
    R = 512; C = 2048; cx = rem & 63; ry = rem >> 6;
  } else if (bid < 12288) {
    const int idx = bid - 8192, z = idx >> 10, rem = idx & 1023;
    src = w2 + (size_t)z * 2048 * 512;
    dst = W2t + (size_t)z * 512 * 2048;
    R = 2048; C = 512; cx = rem & 15; ry = rem >> 4;
  } else {
    const int idx = bid - 12288;
    src = outw; dst = OWt;
    R = 512; C = 128; cx = idx & 3; ry = idx >> 2;
  }
  __shared__ float tile[32][33];
  const int c0 = cx * 32, r0 = ry * 32;
  const int tx = threadIdx.x & 31, ty = threadIdx.x >> 5;
#pragma unroll
  for (int j = 0; j < 4; j++)
    tile[ty + j * 8][tx] = src[(size_t)(r0 + ty + j * 8) * C + c0 + tx];
  __syncthreads();
#pragma unroll
  for (int j = 0; j < 4; j++)
    dst[(size_t)(c0 + ty + j * 8) * R + r0 + tx] = f2b(tile[tx][ty + j * 8]);
}

// ---------------------------------------------------------------------------
// LN-fused GEMM: C = epi(LN(h)[M,512] @ Bt[N,512]^T + bias).
// K = 512 = full row, so LN is block-local: pass-1 computes each of the 128
// rows' mean/rs (2 threads/row, regs); K-loop re-stages normalized bf16
// A-slices (L2-hot h) via regs+ds_write, B streamed via global_load_lds dbuf.
// g/b cached in LDS. One barrier per K-step.
// EPI: 2 = gelu -> bf16, 3 = f32 out, 5 = fused QKV epilogue
//      (col<512 -> q*0.125 bf16, col<1024 -> k bf16, else v -> vt[B][512][S])
// ---------------------------------------------------------------------------
template <int EPI>
__global__ __launch_bounds__(256, 2) void gemm_ln_kernel(
    const float* __restrict__ hsrc, const unsigned short* __restrict__ Bt,
    const float* __restrict__ g, const float* __restrict__ b,
    const float* __restrict__ bias, void* __restrict__ Cout, int N,
    const float* __restrict__ bias2, const float* __restrict__ bias3,
    void* __restrict__ C2, void* __restrict__ C3)
{
  constexpr int LDA = 40;   // padded A stride (80 B: 16B-aligned, 2-way banks)
  __shared__ unsigned short Albuf[2][128 * LDA];
  __shared__ unsigned short Blds[2][128 * 32];
  __shared__ float gbl[1024];              // g[0..512), b[512..1024)
  const int tid = threadIdx.x;
  const int w = tid >> 6, lane = tid & 63, lr = lane & 15, lg = lane >> 4;
  const int m0 = blockIdx.x * 128, n0 = blockIdx.y * 128;
  const int wm = (w >> 1) * 64, wn = (w & 1) * 64;

  // ---- pass 1: per-row mean/rs (thread t owns row rt, half hf) ----
  const int rt = tid >> 1, hf = tid & 1;
  const float* hrow = hsrc + (size_t)(m0 + rt) * 512 + hf * 256;
  float s1 = 0.f, s2 = 0.f;
#pragma unroll 8
  for (int j = 0; j < 64; j++) {
    const float4 v = ((const float4*)hrow)[j];
    s1 += v.x + v.y + v.z + v.w;
    s2 += v.x * v.x + v.y * v.y + v.z * v.z + v.w * v.w;
  }
  s1 += __shfl_xor(s1, 1);
  s2 += __shfl_xor(s2, 1);
  const float mean = s1 * (1.0f / 512.0f);
  const float var = s2 * (1.0f / 512.0f) - mean * mean;
  const float rs = rsqrtf(var + 1e-5f);

  // g/b -> LDS
  *(float2*)&gbl[tid * 2] = *(const float2*)&g[tid * 2];
  *(float2*)&gbl[512 + tid * 2] = *(const float2*)&b[tid * 2];

  // B staging (wave w stages rows [w*32, w*32+32))
  const int srow = w * 32 + (lane >> 2);
  const int scol = (lane & 3) * 8;
  const unsigned short* Bg0 = Bt + (size_t)(n0 + srow) * 512 + scol;
  const unsigned short* Bg1 = Bt + (size_t)(n0 + srow + 16) * 512 + scol;
  const int bl0 = (w * 32) * 32;
  const int bl1 = (w * 32 + 16) * 32;

  float ar[16];
  auto ALOAD = [&](int t) {
    const float* p = hsrc + (size_t)(m0 + rt) * 512 + t * 32 + hf * 16;
#pragma unroll
    for (int i = 0; i < 4; i++) {
      const float4 v = ((const float4*)p)[i];
      ar[i * 4 + 0] = v.x; ar[i * 4 + 1] = v.y;
      ar[i * 4 + 2] = v.z; ar[i * 4 + 3] = v.w;
    }
  };
  auto AWRITE = [&](int buf, int t) {
    const int c0 = t * 32 + hf * 16;
    unsigned short tmp[16];
#pragma unroll
    for (int i = 0; i < 4; i++) {
      const f32x4 gv = *(const f32x4*)&gbl[c0 + i * 4];
      const f32x4 bv = *(const f32x4*)&gbl[512 + c0 + i * 4];
#pragma unroll
      for (int j = 0; j < 4; j++)
        tmp[i * 4 + j] = f2b((ar[i * 4 + j] - mean) * rs * gv[j] + bv[j]);
    }
    unsigned short* d = &Albuf[buf][rt * LDA + hf * 16];
    *(int4*)d = *(const int4*)tmp;
    *(int4*)(d + 8) = *(const int4*)(tmp + 8);
  };
  auto STAGE_B = [&](int buf, int t) {
    const int kt = t * 32;
    gload16(Bg0 + kt, &Blds[buf][bl0]);
    gload16(Bg1 + kt, &Blds[buf][bl1]);
  };

  const f32x4 zero4 = {0.f, 0.f, 0.f, 0.f};
  f32x4 acc[4][4];
#pragma unroll
  for (int i = 0; i < 4; i++)
#pragma unroll
    for (int j = 0; j < 4; j++) acc[i][j] = zero4;

  __syncthreads();            // gbl ready
  ALOAD(0);
  AWRITE(0, 0);
  STAGE_B(0, 0);
  __syncthreads();            // A0 ds_writes + B0 gloads drained
  int cur = 0;
  for (int t = 0; t < 16; t++) {
    if (t + 1 < 16) {
      ALOAD(t + 1);           // issue global reads early (L2-hot)
      STAGE_B(cur ^ 1, t + 1);
    }
    bf16x8 af[4], bfr[4];
#pragma unroll
    for (int mi = 0; mi < 4; mi++)
      af[mi] = *(const bf16x8*)(&Albuf[cur][(wm + mi * 16 + lr) * LDA + lg * 8]);
#pragma unroll
    for (int ni = 0; ni < 4; ni++)
      bfr[ni] = *(const bf16x8*)(&Blds[cur][(wn + ni * 16 + lr) * 32 + lg * 8]);
#pragma unroll
    for (int mi = 0; mi < 4; mi++)
#pragma unroll
      for (int ni = 0; ni < 4; ni++)
        acc[mi][ni] = __builtin_amdgcn_mfma_f32_16x16x32_bf16(af[mi], bfr[ni], acc[mi][ni], 0, 0, 0);
    if (t + 1 < 16) AWRITE(cur ^ 1, t + 1);
    __syncthreads();          // drain: next A/B ready, all reads of cur done
    cur ^= 1;
  }

#pragma unroll
  for (int mi = 0; mi < 4; mi++) {
#pragma unroll
    for (int ni = 0; ni < 4; ni++) {
      const int col = n0 + wn + ni * 16 + lr;
      if constexpr (EPI == 5) {
        if (col < 512) {
          const float bs = bias[col];
#pragma unroll
          for (int r = 0; r < 4; r++) {
            const int row = m0 + wm + mi * 16 + lg * 4 + r;
            ((unsigned short*)Cout)[(size_t)row * 512 + col] =
                f2b((acc[mi][ni][r] + bs) * 0.125f);
          }
        } else if (col < 1024) {
          const float bs = bias2[col - 512];
#pragma unroll
          for (int r = 0; r < 4; r++) {
            const int row = m0 + wm + mi * 16 + lg * 4 + r;
            ((unsigned short*)C2)[(size_t)row * 512 + (col - 512)] =
                f2b(acc[mi][ni][r] + bs);
          }
        } else {
          const float bs = bias3[col - 1024];
          const int row0_ = m0 + wm + mi * 16 + lg * 4;
          const int bb = row0_ >> 10, ssi = row0_ & 1023;
          ushort4 pk;
          pk.x = f2b(acc[mi][ni][0] + bs);
          pk.y = f2b(acc[mi][ni][1] + bs);
          pk.z = f2b(acc[mi][ni][2] + bs);
          pk.w = f2b(acc[mi][ni][3] + bs);
          *(ushort4*)((unsigned short*)C3 + ((size_t)(bb * 512 + (col - 1024))) * 1024 + ssi) = pk;
        }
      } else {
        const float bs = bias[col];
#pragma unroll
        for (int r = 0; r < 4; r++) {
          const int row = m0 + wm + mi * 16 + lg * 4 + r;
          float val = acc[mi][ni][r] + bs;
          const size_t idx = (size_t)row * N + col;
          if constexpr (EPI == 2) {
            val = 0.5f * val * (1.0f + erff(val * 0.7071067811865475f));
            ((unsigned short*)Cout)[idx] = f2b(val);
          } else {  // 3
            ((float*)Cout)[idx] = val;
          }
        }
      }
    }
  }
}

// ---------------------------------------------------------------------------
// Residual GEMM: C[M,N](f32) += A[M,K](bf16) @ Bt[N,K]^T + bias. Single writer
// (no split-K, no atomics). 2-phase dbuf via global_load_lds, BK=32.
// ---------------------------------------------------------------------------
__global__ __launch_bounds__(256, 2) void gemm_res_kernel(
    const unsigned short* __restrict__ A, const unsigned short* __restrict__ Bt,
    const float* __restrict__ bias, float* __restrict__ Cout,
    int N, int K)
{
  __shared__ unsigned short Alds[2][128 * 32];
  __shared__ unsigned short Blds[2][128 * 32];
  const int tid = threadIdx.x;
  const int w = tid >> 6, lane = tid & 63, lr = lane & 15, lg = lane >> 4;
  const int m0 = blockIdx.x * 128, n0 = blockIdx.y * 128;
  const int wm = (w >> 1) * 64, wn = (w & 1) * 64;

  const int srow = w * 32 + (lane >> 2);
  const int scol = (lane & 3) * 8;
  const unsigned short* Ag0 = A + (size_t)(m0 + srow) * K + scol;
  const unsigned short* Ag1 = A + (size_t)(m0 + srow + 16) * K + scol;
  const unsigned short* Bg0 = Bt + (size_t)(n0 + srow) * K + scol;
  const unsigned short* Bg1 = Bt + (size_t)(n0 + srow + 16) * K + scol;
  const int l0 = (w * 32) * 32;
  const int l1 = (w * 32 + 16) * 32;

  auto STAGE = [&](int buf, int kt) {
    gload16(Ag0 + kt, &Alds[buf][l0]);
    gload16(Ag1 + kt, &Alds[buf][l1]);
    gload16(Bg0 + kt, &Blds[buf][l0]);
    gload16(Bg1 + kt, &Blds[buf][l1]);
  };

  const f32x4 zero4 = {0.f, 0.f, 0.f, 0.f};
  f32x4 acc[4][4];
#pragma unroll
  for (int i = 0; i < 4; i++)
#pragma unroll
    for (int j = 0; j < 4; j++) acc[i][j] = zero4;

  const int nsteps = K >> 5;
  STAGE(0, 0);
  __syncthreads();
  int cur = 0;
  for (int t = 0; t < nsteps; t++) {
    if (t + 1 < nsteps) STAGE(cur ^ 1, (t + 1) * 32);
    bf16x8 af[4], bfr[4];
#pragma unroll
    for (int mi = 0; mi < 4; mi++)
      af[mi] = *(const bf16x8*)(&Alds[cur][(wm + mi * 16 + lr) * 32 + lg * 8]);
#pragma unroll
    for (int ni = 0; ni < 4; ni++)
      bfr[ni] = *(const bf16x8*)(&Blds[cur][(wn + ni * 16 + lr) * 32 + lg * 8]);
#pragma unroll
    for (int mi = 0; mi < 4; mi++)
#pragma unroll
      for (int ni = 0; ni < 4; ni++)
        acc[mi][ni] = __builtin_amdgcn_mfma_f32_16x16x32_bf16(af[mi], bfr[ni], acc[mi][ni], 0, 0, 0);
    __syncthreads();
    cur ^= 1;
  }

#pragma unroll
  for (int mi = 0; mi < 4; mi++) {
#pragma unroll
    for (int ni = 0; ni < 4; ni++) {
      const int col = n0 + wn + ni * 16 + lr;
      const float bs = bias[col];
#pragma unroll
      for (int r = 0; r < 4; r++) {
        const int row = m0 + wm + mi * 16 + lg * 4 + r;
        Cout[(size_t)row * N + col] += acc[mi][ni][r] + bs;
      }
    }
  }
}

// ---------------------------------------------------------------------------
// Fused attention (unchanged from R5): scores -> exact top-k (ballot binary
// search) + softmax -> probs f32 to d_out + bf16 in LDS -> PV split-K.
// ---------------------------------------------------------------------------
__global__ __launch_bounds__(256, 2) void attn_fused_kernel(
    const unsigned short* __restrict__ qbf, const unsigned short* __restrict__ kbf,
    const unsigned short* __restrict__ vt, float* __restrict__ attnL,
    unsigned short* __restrict__ obf)
{
  constexpr int LDF = 1032;                 // padded f32 row stride
  __shared__ float sc[16 * LDF];            // 66 KB
  const int mblk = blockIdx.x, bnh = blockIdx.y;
  const int b = bnh >> 3, nh = bnh & 7;
  const int tid = threadIdx.x, w = tid >> 6, lane = tid & 63;
  const int lr = lane & 15, lg = lane >> 4;
  const int row0 = mblk * 16;

  const unsigned short* qbase = qbf + ((size_t)(b * S_ + row0)) * H_ + nh * HD_;
  const unsigned short* kbase = kbf + (size_t)(b * S_) * H_ + nh * HD_;

  const f32x4 zero4 = {0.f, 0.f, 0.f, 0.f};

  // ---- Phase 1: scores ----
  {
    f32x4 acc[16];
#pragma unroll
    for (int kt = 0; kt < 16; kt++) acc[kt] = zero4;
    bf16x8 qf[2];
    qf[0] = *(const bf16x8*)(qbase + (size_t)lr * H_ + lg * 8);
    qf[1] = *(const bf16x8*)(qbase + (size_t)lr * H_ + 32 + lg * 8);
    const int kw0 = w * 256;
#pragma unroll
    for (int kt = 0; kt < 16; kt++) {
      const unsigned short* kp = kbase + (size_t)(kw0 + kt * 16 + lr) * H_ + lg * 8;
      const bf16x8 kf0 = *(const bf16x8*)(kp);
      const bf16x8 kf1 = *(const bf16x8*)(kp + 32);
      acc[kt] = __builtin_amdgcn_mfma_f32_16x16x32_bf16(kf0, qf[0], acc[kt], 0, 0, 0);
      acc[kt] = __builtin_amdgcn_mfma_f32_16x16x32_bf16(kf1, qf[1], acc[kt], 0, 0, 0);
    }
#pragma unroll
    for (int kt = 0; kt < 16; kt++)
      *(f32x4*)(sc + (size_t)lr * LDF + kw0 + kt * 16 + lg * 4) = acc[kt];
  }
  __syncthreads();

  // ---- Phase 2: exact k-th largest (ballot binary search) + softmax ----
#pragma unroll 1
  for (int rr = 0; rr < 4; rr++) {
    const int row = w * 4 + rr;
    float* rowp = sc + (size_t)row * LDF;
    float v[16];
#pragma unroll
    for (int j = 0; j < 8; j++) {
      const float2 t2 = *(const float2*)(rowp + 2 * lane + j * 128);
      v[2 * j] = t2.x; v[2 * j + 1] = t2.y;
    }
    unsigned int keys[16];
#pragma unroll
    for (int j = 0; j < 16; j++) {
      const unsigned int u = __float_as_uint(v[j]);
      keys[j] = (u & 0x80000000u) ? ~u : (u | 0x80000000u);
    }
    unsigned int prefix = 0u;
#pragma unroll 1
    for (int bit = 31; bit >= 0; bit--) {
      const unsigned int cand = prefix | (1u << bit);
      int cnt = 0;
#pragma unroll
      for (int j = 0; j < 16; j++)
        cnt += (int)__popcll(__ballot(keys[j] >= cand));
      if (cnt >= KTOP_) prefix = cand;
    }
    const unsigned int fb = (prefix & 0x80000000u) ? (prefix & 0x7fffffffu) : ~prefix;
    const float thresh = __uint_as_float(fb);

    float mx = v[0];
#pragma unroll
    for (int j = 1; j < 16; j++) mx = fmaxf(mx, v[j]);
#pragma unroll
    for (int m = 1; m < 64; m <<= 1) mx = fmaxf(mx, __shfl_xor(mx, m));
    float p[16];
    float ssum = 0.f;
#pragma unroll
    for (int j = 0; j < 16; j++) {
      const float e = expf(v[j] - mx);
      p[j] = (v[j] >= thresh) ? e : 0.f;
      ssum += p[j];
    }
#pragma unroll
    for (int m = 1; m < 64; m <<= 1) ssum += __shfl_xor(ssum, m);
    const float inv = 1.0f / ssum;
    float* outrow = attnL + (size_t)bnh * S_ * S_ + (size_t)(row0 + row) * S_;
    unsigned short* prow = (unsigned short*)rowp;
#pragma unroll
    for (int j = 0; j < 8; j++) {
      const float p0 = p[2 * j] * inv, p1 = p[2 * j + 1] * inv;
      *(float2*)(outrow + 2 * lane + j * 128) = make_float2(p0, p1);
      const unsigned int pk = ((unsigned int)f2b(p1) << 16) | (unsigned int)f2b(p0);
      *(unsigned int*)(prow + 2 * lane + j * 128) = pk;
    }
  }
  __syncthreads();

  // ---- Phase 3: PV split-K across waves ----
  const unsigned short* vb = vt + (size_t)(b * 512 + nh * HD_) * S_;
  f32x4 oacc[4];
#pragma unroll
  for (int ni = 0; ni < 4; ni++) oacc[ni] = zero4;
  const unsigned short* scu = (const unsigned short*)sc;
#pragma unroll
  for (int ks = 0; ks < 8; ks++) {
    const int k0 = w * 256 + ks * 32;
    const bf16x8 pf = *(const bf16x8*)(scu + (size_t)lr * (2 * LDF) + k0 + lg * 8);
    bf16x8 vfr[4];
#pragma unroll
    for (int ni = 0; ni < 4; ni++)
      vfr[ni] = *(const bf16x8*)(vb + (size_t)(ni * 16 + lr) * S_ + k0 + lg * 8);
#pragma unroll
    for (int ni = 0; ni < 4; ni++)
      oacc[ni] = __builtin_amdgcn_mfma_f32_16x16x32_bf16(pf, vfr[ni], oacc[ni], 0, 0, 0);
  }
  __syncthreads();
  float* red = sc + w * 1024;
#pragma unroll
  for (int ni = 0; ni < 4; ni++)
#pragma unroll
    for (int r = 0; r < 4; r++)
      red[(lg * 4 + r) * 64 + ni * 16 + lr] = oacc[ni][r];
  __syncthreads();
  {
    const int orow = tid >> 4, oc0 = (tid & 15) * 4;
    const float* rp = sc + orow * 64 + oc0;
    float4 s0 = *(const float4*)rp;
#pragma unroll
    for (int ww = 1; ww < 4; ww++) {
      const float4 a = *(const float4*)(rp + ww * 1024);
      s0.x += a.x; s0.y += a.y; s0.z += a.z; s0.w += a.w;
    }
    ushort4 o1;
    o1.x = f2b(s0.x); o1.y = f2b(s0.y); o1.z = f2b(s0.z); o1.w = f2b(s0.w);
    unsigned short* dst = obf + (size_t)(b * S_ + row0 + orow) * H_ + nh * HD_ + oc0;
    *(ushort4*)dst = o1;
  }
}

// ---------------------------------------------------------------------------
extern "C" void kernel_launch(void* const* d_in, const int* in_sizes, int n_in,
                              void* d_out, int out_size, void* d_ws, size_t ws_size,
                              hipStream_t stream)
{
  (void)in_sizes; (void)n_in; (void)out_size; (void)ws_size;
  const float* x     = (const float*)d_in[0];
  const float* in_w  = (const float*)d_in[1];
  const float* in_b  = (const float*)d_in[2];
  const float* ln1_g = (const float*)d_in[3];
  const float* ln1_b = (const float*)d_in[4];
  const float* qw    = (const float*)d_in[5];
  const float* qbias = (const float*)d_in[6];
  const float* kw    = (const float*)d_in[7];
  const float* kbias = (const float*)d_in[8];
  const float* vw    = (const float*)d_in[9];
  const float* vbias = (const float*)d_in[10];
  const float* ow    = (const float*)d_in[11];
  const float* obias = (const float*)d_in[12];
  const float* ln2_g = (const float*)d_in[13];
  const float* ln2_b = (const float*)d_in[14];
  const float* w1    = (const float*)d_in[15];
  const float* b1    = (const float*)d_in[16];
  const float* w2    = (const float*)d_in[17];
  const float* b2    = (const float*)d_in[18];
  const float* fn_g  = (const float*)d_in[19];
  const float* fn_b  = (const float*)d_in[20];
  const float* out_w = (const float*)d_in[21];
  const float* out_b = (const float*)d_in[22];

  char* ws = (char*)d_ws;
  size_t off = 0;
  auto alloc = [&](size_t bytes) -> void* {
    void* p = ws + off;
    off += (bytes + 255) & ~(size_t)255;
    return p;
  };
  float* h             = (float*)alloc((size_t)BS_ * H_ * 4);
  unsigned short* Wqkvt = (unsigned short*)alloc((size_t)L_ * 1536 * H_ * 2);
  unsigned short* Wot  = (unsigned short*)alloc((size_t)L_ * H_ * H_ * 2);
  unsigned short* W1t  = (unsigned short*)alloc((size_t)L_ * MLP_ * H_ * 2);
  unsigned short* W2t  = (unsigned short*)alloc((size_t)L_ * H_ * MLP_ * 2);
  unsigned short* OWt  = (unsigned short*)alloc((size_t)OUT_ * H_ * 2);
  unsigned short* qbf  = (unsigned short*)alloc((size_t)BS_ * H_ * 2);
  unsigned short* kbf  = (unsigned short*)alloc((size_t)BS_ * H_ * 2);
  unsigned short* vtb  = (unsigned short*)alloc((size_t)B_ * 512 * S_ * 2);
  unsigned short* obf  = (unsigned short*)alloc((size_t)BS_ * H_ * 2);
  unsigned short* tbf  = (unsigned short*)alloc((size_t)BS_ * MLP_ * 2);

  float* attn_base = (float*)d_out + (size_t)BS_ * OUT_;

  const dim3 tb(256);
  prep_kernel<<<dim3(13376), tb, 0, stream>>>(
      qw, kw, vw, ow, w1, w2, out_w, x, in_w, in_b,
      Wqkvt, Wot, W1t, W2t, OWt, h);

  for (int l = 0; l < L_; l++) {
    float* attnL = attn_base + (size_t)l * 16 * S_ * S_;
    gemm_ln_kernel<5><<<dim3(16, 12), tb, 0, stream>>>(
        h, Wqkvt + (size_t)l * 1536 * H_, ln1_g + l * H_, ln1_b + l * H_,
        qbias + l * H_, qbf, 1536,
        kbias + l * H_, vbias + l * H_, kbf, vtb);
    attn_fused_kernel<<<dim3(64, 16), tb, 0, stream>>>(qbf, kbf, vtb, attnL, obf);
    gemm_res_kernel<<<dim3(16, 4), tb, 0, stream>>>(
        obf, Wot + (size_t)l * H_ * H_, obias + l * H_, h, H_, H_);
    gemm_ln_kernel<2><<<dim3(16, 16), tb, 0, stream>>>(
        h, W1t + (size_t)l * MLP_ * H_, ln2_g + l * H_, ln2_b + l * H_,
        b1 + l * MLP_, tbf, MLP_,
        nullptr, nullptr, nullptr, nullptr);
    gemm_res_kernel<<<dim3(16, 4), tb, 0, stream>>>(
        tbf, W2t + (size_t)l * H_ * MLP_, b2 + l * H_, h, H_, MLP_);
  }

  gemm_ln_kernel<3><<<dim3(16, 1), tb, 0, stream>>>(
      h, OWt, fn_g, fn_b, out_b, d_out, OUT_,
      nullptr, nullptr, nullptr, nullptr);
}